// Round 1
// baseline (83.530 us; speedup 1.0000x reference)
//
#include <hip/hip_runtime.h>

// Depthwise conv (K=5, R=2) over packed varlen sequences + bias + residual.
// x: [T, C] f32, weight: [C, K] f32, bias: [C] f32, cu_seqlens: [N_SEQS+1] i32.
// out[t,c] = x[t,c] + bias[c] + sum_k w[c,k] * x[t+k-2, c] * [same segment]

#define T_DIM 65536
#define C_DIM 768
#define C4    192     // C / 4
#define ROWS  32      // rows per block; T_DIM % ROWS == 0 -> 2048 blocks

__global__ __launch_bounds__(192) void dwconv5_kernel(
    const float4* __restrict__ x4,    // [T][C4]
    const float*  __restrict__ w,     // [C][5]
    const float4* __restrict__ b4,    // [C4]
    const int*    __restrict__ cu,    // [17]
    float4*       __restrict__ o4)    // [T][C4]
{
    const int c4 = threadIdx.x;           // 0..191, this thread's float4 column
    const int t0 = blockIdx.x * ROWS;

    // Per-thread weights: channels 4*c4..4*c4+3, 5 taps each -> 20 contiguous
    // floats starting at 80-byte (16B-aligned) offset. Load as 5 float4.
    float wt[5][4];   // [tap][channel]
    {
        const float4* wv = (const float4*)w + c4 * 5;
        float tmp[20];
#pragma unroll
        for (int i = 0; i < 5; ++i) {
            float4 v = wv[i];
            tmp[4*i+0] = v.x; tmp[4*i+1] = v.y; tmp[4*i+2] = v.z; tmp[4*i+3] = v.w;
        }
#pragma unroll
        for (int k = 0; k < 5; ++k)
#pragma unroll
            for (int j = 0; j < 4; ++j)
                wt[k][j] = tmp[j*5 + k];
    }
    const float4 bb = b4[c4];

    // Segment bounds containing t0 (block-uniform; reproduces searchsorted
    // side='right' incl. empty segments from duplicate boundaries).
    int s = 0;
    while (cu[s+1] <= t0) ++s;
    int lo = cu[s], hi = cu[s+1];

    auto ld = [&](int t) -> float4 {
        int tc = t < 0 ? 0 : (t > T_DIM - 1 ? T_DIM - 1 : t);   // clamp; masked later
        return x4[(size_t)tc * C4 + c4];
    };

    // Sliding window: v0..v4 hold rows t-2..t+2 for current t.
    float4 v0 = ld(t0-2), v1 = ld(t0-1), v2 = ld(t0), v3 = ld(t0+1), v4 = ld(t0+2);

#define TAP(acc, v, k)                                   \
    do {                                                 \
        acc.x = fmaf((v).x, wt[k][0], acc.x);            \
        acc.y = fmaf((v).y, wt[k][1], acc.y);            \
        acc.z = fmaf((v).z, wt[k][2], acc.z);            \
        acc.w = fmaf((v).w, wt[k][3], acc.w);            \
    } while (0)

#pragma unroll 4
    for (int r = 0; r < ROWS; ++r) {
        const int t = t0 + r;
        float4 vn = ld(t + 3);            // prefetch next window row (1-deep pipeline)

        if (t >= hi) {                    // advance segment (uniform branch)
            do { ++s; } while (cu[s+1] <= t);
            lo = cu[s]; hi = cu[s+1];
        }

        // residual + bias + center tap (always valid)
        float4 acc;
        acc.x = fmaf(v2.x, wt[2][0], v2.x + bb.x);
        acc.y = fmaf(v2.y, wt[2][1], v2.y + bb.y);
        acc.z = fmaf(v2.z, wt[2][2], v2.z + bb.z);
        acc.w = fmaf(v2.w, wt[2][3], v2.w + bb.w);

        // boundary-masked taps (t, lo, hi uniform -> scalar branches)
        if (t - 2 >= lo) TAP(acc, v0, 0);
        if (t - 1 >= lo) TAP(acc, v1, 1);
        if (t + 1 <  hi) TAP(acc, v3, 3);
        if (t + 2 <  hi) TAP(acc, v4, 4);

        o4[(size_t)t * C4 + c4] = acc;

        v0 = v1; v1 = v2; v2 = v3; v3 = v4; v4 = vn;
    }
#undef TAP
}

extern "C" void kernel_launch(void* const* d_in, const int* in_sizes, int n_in,
                              void* d_out, int out_size, void* d_ws, size_t ws_size,
                              hipStream_t stream) {
    const float4* x4 = (const float4*)d_in[0];
    const float*  w  = (const float*)d_in[1];
    const float4* b4 = (const float4*)d_in[2];
    const int*    cu = (const int*)d_in[3];
    float4*       o4 = (float4*)d_out;

    dwconv5_kernel<<<dim3(T_DIM / ROWS), dim3(192), 0, stream>>>(x4, w, b4, cu, o4);
}

// Round 3
// 64.998 us; speedup vs baseline: 1.2851x; 1.2851x over previous
//
#include <hip/hip_runtime.h>

// Depthwise conv (K=5, R=2) over packed varlen sequences + bias + residual.
// x: [T, C] f32, weight: [C, K] f32, bias: [C] f32, cu_seqlens: [N_SEQS+1] i32.
// out[t,c] = x[t,c] + bias[c] + sum_k w[c,k] * x[t+k-2, c] * [same segment]
//
// Memory-bound: 192 MiB in + 192 MiB out -> ~64 us floor at 6.3 TB/s.
// R2: ROWS 32->64 (halo 15.6%->7.8%), XCD-chunked block swizzle (adjacent
// row-blocks share halo rows in the same XCD L2), nontemporal output stores
// (out is write-once, keep it from thrashing L2/LLC).
// R3: ext_vector_type float4 so __builtin_nontemporal_store compiles.

#define T_DIM 65536
#define C_DIM 768
#define C4    192     // C / 4
#define ROWS  64      // rows per block -> 1024 blocks (divisible by 8 XCDs)
#define NXCD  8

typedef float f4 __attribute__((ext_vector_type(4)));

__global__ __launch_bounds__(192) void dwconv5_kernel(
    const f4* __restrict__ x4,    // [T][C4]
    const f4* __restrict__ w4,    // weight [C][5] viewed as f4, 5 f4 per thread
    const f4* __restrict__ b4,    // [C4]
    const int* __restrict__ cu,   // [17]
    f4*       __restrict__ o4)    // [T][C4]
{
    const int c4 = threadIdx.x;           // 0..191, this thread's float4 column

    // XCD-chunked swizzle: hardware round-robins blockIdx across 8 XCDs;
    // remap so each XCD owns a contiguous chunk of row-blocks -> halo rows
    // shared by adjacent blocks hit the same XCD's L2. Bijective (1024%8==0).
    const int nwg = T_DIM / ROWS;
    const int bid = (int)blockIdx.x;
    const int swz = (bid % NXCD) * (nwg / NXCD) + bid / NXCD;
    const int t0  = swz * ROWS;

    // Per-thread weights: channels 4*c4..4*c4+3, 5 taps each -> 20 contiguous
    // floats at 16B-aligned offset. Load as 5 f4, transpose to [tap][ch].
    float wt[5][4];
    {
        const f4* wv = w4 + c4 * 5;
        float tmp[20];
#pragma unroll
        for (int i = 0; i < 5; ++i) {
            f4 v = wv[i];
            tmp[4*i+0] = v.x; tmp[4*i+1] = v.y; tmp[4*i+2] = v.z; tmp[4*i+3] = v.w;
        }
#pragma unroll
        for (int k = 0; k < 5; ++k)
#pragma unroll
            for (int j = 0; j < 4; ++j)
                wt[k][j] = tmp[j*5 + k];
    }
    const f4 bb = b4[c4];

    // Segment bounds containing t0 (block-uniform; reproduces searchsorted
    // side='right' incl. empty segments from duplicate boundaries).
    int s = 0;
    while (cu[s+1] <= t0) ++s;
    int lo = cu[s], hi = cu[s+1];

    auto ld = [&](int t) -> f4 {
        int tc = t < 0 ? 0 : (t > T_DIM - 1 ? T_DIM - 1 : t);   // clamp; masked later
        return x4[(size_t)tc * C4 + c4];
    };

    // Sliding window: v0..v4 hold rows t-2..t+2 for current t.
    f4 v0 = ld(t0-2), v1 = ld(t0-1), v2 = ld(t0), v3 = ld(t0+1), v4 = ld(t0+2);

#define TAP(acc, v, k)                                   \
    do {                                                 \
        acc.x = fmaf((v).x, wt[k][0], acc.x);            \
        acc.y = fmaf((v).y, wt[k][1], acc.y);            \
        acc.z = fmaf((v).z, wt[k][2], acc.z);            \
        acc.w = fmaf((v).w, wt[k][3], acc.w);            \
    } while (0)

#pragma unroll 4
    for (int r = 0; r < ROWS; ++r) {
        const int t = t0 + r;
        f4 vn = ld(t + 3);                // prefetch next window row

        if (t >= hi) {                    // advance segment (uniform branch)
            do { ++s; } while (cu[s+1] <= t);
            lo = cu[s]; hi = cu[s+1];
        }

        // residual + bias + center tap (always valid)
        f4 acc;
        acc.x = fmaf(v2.x, wt[2][0], v2.x + bb.x);
        acc.y = fmaf(v2.y, wt[2][1], v2.y + bb.y);
        acc.z = fmaf(v2.z, wt[2][2], v2.z + bb.z);
        acc.w = fmaf(v2.w, wt[2][3], v2.w + bb.w);

        // boundary-masked taps (t, lo, hi uniform -> scalar branches)
        if (t - 2 >= lo) TAP(acc, v0, 0);
        if (t - 1 >= lo) TAP(acc, v1, 1);
        if (t + 1 <  hi) TAP(acc, v3, 3);
        if (t + 2 <  hi) TAP(acc, v4, 4);

        __builtin_nontemporal_store(acc, &o4[(size_t)t * C4 + c4]);

        v0 = v1; v1 = v2; v2 = v3; v3 = v4; v4 = vn;
    }
#undef TAP
}

extern "C" void kernel_launch(void* const* d_in, const int* in_sizes, int n_in,
                              void* d_out, int out_size, void* d_ws, size_t ws_size,
                              hipStream_t stream) {
    const f4*  x4 = (const f4*)d_in[0];
    const f4*  w4 = (const f4*)d_in[1];
    const f4*  b4 = (const f4*)d_in[2];
    const int* cu = (const int*)d_in[3];
    f4*        o4 = (f4*)d_out;

    dwconv5_kernel<<<dim3(T_DIM / ROWS), dim3(192), 0, stream>>>(x4, w4, b4, cu, o4);
}